// Round 13
// baseline (119.530 us; speedup 1.0000x reference)
//
#include <hip/hip_runtime.h>

#define NN 512
#define DIN 64
#define DH 32
#define HSTR 520   // h_t row stride (pad: 260 dw == 4 mod 32, keeps 16B alignment)

typedef __attribute__((ext_vector_type(8))) short short8;
typedef __attribute__((ext_vector_type(4))) short short4v;
typedef __attribute__((ext_vector_type(4))) float f32x4;

__device__ __forceinline__ float bf2f(unsigned short u) {
    return __uint_as_float(((unsigned)u) << 16);
}
__device__ __forceinline__ unsigned short f2bf(float x) {
    unsigned u = __float_as_uint(x);
    u += 0x7FFF + ((u >> 16) & 1);
    return (unsigned short)(u >> 16);
}
// packed RNE f32x2 -> bf16x2 (1 VALU op vs ~4 for scalar f2bf; same rounding)
__device__ __forceinline__ unsigned cvt_pk_bf16(float lo, float hi) {
    unsigned r;
    asm("v_cvt_pk_bf16_f32 %0, %1, %2" : "=v"(r) : "v"(lo), "v"(hi));
    return r;
}

// One block per (head, batch). 512 threads = 8 waves. R5-proven grid.
// TOOLCHAIN RULE (verified twice, R2-R4): 1024-thread blocks pin VGPR=64 regardless
// of __launch_bounds__ 2nd arg -> massive scratch spill. Never use 1024-thr blocks.
// VALU diet ladder (phase B is VALU-issue-bound; each ~25% cut ~ -3us):
//  R8:  exp(lrelu(s+t)) == max(e^t e^s, e^.2t e^.2s); cvt_pk pack       [-3.0us]
//  R9:  self-mask peeled to 2/16 kb; phase-A cvt_pk                     [-3.6us]
//  R10: row-scale cancellation: w' = max(e^s, e^{-.8t} e^{.2s})         [-3.3us]
//  R11: MFMA-rowsum denominator -> NaN on HW (unexplained). REVERTED.
//  R12: f32x2 pair math: +2.5us (compiler didn't pack). REVERTED.
//  R13: SCORES VIA MFMA: e_src = x·(W a_src) — precompute w_src/w_tar, put them
//       in cols 0/1 of a third B-fragment (cols 2-15 zero), 2 extra MFMAs per
//       mi-tile replace the 128-shfl butterfly reduce + ps/pt math entirely.
__global__ __launch_bounds__(512) void attn_kernel(
    const float* __restrict__ in_g,    // [B,512,64]
    const float* __restrict__ lin_g,   // [H,64,32]
    const float* __restrict__ asrc_g,  // [H,32]
    const float* __restrict__ atar_g,  // [H,32]
    float* __restrict__ msgs8)         // [B*8][512][32] fp32, slice = blockIdx.x
{
    __shared__ unsigned short h_t[DH * HSTR];       // 33280 B: h_t[c*HSTR + m] = h[m][c]
    __shared__ float e1s[NN], e2s[NN];              // j-side: e^s, e^{0.2s}
    __shared__ float rhot[NN];                      // i-side: e^{-0.8 t}
    __shared__ float dinv[NN];
    __shared__ float wsrc[DIN], wtar[DIN];          // W @ a_src, W @ a_tar

    const int t = threadIdx.x;
    const int lane = t & 63, wv = t >> 6;
    const int l15 = lane & 15, quad = lane >> 4;
    const int hIdx = blockIdx.x & 7, bIdx = blockIdx.x >> 3;

    // ---------- Precompute w_src = W @ a_src, w_tar = W @ a_tar (wave 0) ----------
    if (t < 64) {
        const float* lp = lin_g + hIdx * (DIN * DH);
        const float* as = asrc_g + hIdx * 32;
        const float* at = atar_g + hIdx * 32;
        float s1 = 0.f, s2 = 0.f;
        #pragma unroll 8
        for (int k = 0; k < 32; ++k) {
            float w = lp[t * DH + k];
            s1 += w * as[k];
            s2 += w * at[k];
        }
        wsrc[t] = s1;
        wtar[t] = s2;
    }

    // ---------- Phase A: projection h = x @ W via MFMA ----------
    short8 bfrag[2][2];
    {
        const float* lp = lin_g + hIdx * (DIN * DH);
        for (int nt = 0; nt < 2; ++nt)
            for (int ks = 0; ks < 2; ++ks) {
                union { unsigned u[4]; short8 s8; } bu;
                #pragma unroll
                for (int jp = 0; jp < 4; ++jp) {
                    float lo = lp[(ks * 32 + quad * 8 + 2 * jp)     * DH + l15 + nt * 16];
                    float hi = lp[(ks * 32 + quad * 8 + 2 * jp + 1) * DH + l15 + nt * 16];
                    bu.u[jp] = cvt_pk_bf16(lo, hi);
                }
                bfrag[nt][ks] = bu.s8;
            }
    }
    __syncthreads();   // wsrc/wtar ready

    // score B-fragment: col 0 = w_src, col 1 = w_tar, cols 2-15 = 0
    short8 sfrag[2];
    #pragma unroll
    for (int ks = 0; ks < 2; ++ks) {
        union { unsigned u[4]; short8 s8; } su;
        #pragma unroll
        for (int jp = 0; jp < 4; ++jp) {
            int k0 = ks * 32 + quad * 8 + 2 * jp;
            float lo = (l15 == 0) ? wsrc[k0]     : (l15 == 1) ? wtar[k0]     : 0.f;
            float hi = (l15 == 0) ? wsrc[k0 + 1] : (l15 == 1) ? wtar[k0 + 1] : 0.f;
            su.u[jp] = cvt_pk_bf16(lo, hi);
        }
        sfrag[ks] = su.s8;
    }

    const float* xb = in_g + (size_t)bIdx * (NN * DIN);
    for (int mi = 0; mi < 4; ++mi) {
        int mt = wv * 4 + mi;
        int row = mt * 16 + l15;
        const float* rp = xb + row * DIN + quad * 8;
        f32x4 x0 = *((const f32x4*)rp);
        f32x4 x1 = *((const f32x4*)(rp + 4));
        f32x4 x2 = *((const f32x4*)(rp + 32));
        f32x4 x3 = *((const f32x4*)(rp + 36));
        union { unsigned u[4]; short8 s8; } ua0, ua1;
        ua0.u[0] = cvt_pk_bf16(x0[0], x0[1]);
        ua0.u[1] = cvt_pk_bf16(x0[2], x0[3]);
        ua0.u[2] = cvt_pk_bf16(x1[0], x1[1]);
        ua0.u[3] = cvt_pk_bf16(x1[2], x1[3]);
        ua1.u[0] = cvt_pk_bf16(x2[0], x2[1]);
        ua1.u[1] = cvt_pk_bf16(x2[2], x2[3]);
        ua1.u[2] = cvt_pk_bf16(x3[0], x3[1]);
        ua1.u[3] = cvt_pk_bf16(x3[2], x3[3]);
        f32x4 c0 = {0.f, 0.f, 0.f, 0.f}, c1 = {0.f, 0.f, 0.f, 0.f};
        f32x4 e  = {0.f, 0.f, 0.f, 0.f};
        c0 = __builtin_amdgcn_mfma_f32_16x16x32_bf16(ua0.s8, bfrag[0][0], c0, 0, 0, 0);
        c0 = __builtin_amdgcn_mfma_f32_16x16x32_bf16(ua1.s8, bfrag[0][1], c0, 0, 0, 0);
        c1 = __builtin_amdgcn_mfma_f32_16x16x32_bf16(ua0.s8, bfrag[1][0], c1, 0, 0, 0);
        c1 = __builtin_amdgcn_mfma_f32_16x16x32_bf16(ua1.s8, bfrag[1][1], c1, 0, 0, 0);
        e  = __builtin_amdgcn_mfma_f32_16x16x32_bf16(ua0.s8, sfrag[0],    e,  0, 0, 0);
        e  = __builtin_amdgcn_mfma_f32_16x16x32_bf16(ua1.s8, sfrag[1],    e,  0, 0, 0);
        #pragma unroll
        for (int r = 0; r < 4; ++r) {
            int m = mt * 16 + quad * 4 + r;
            h_t[l15 * HSTR + m]        = f2bf(c0[r]);
            h_t[(l15 + 16) * HSTR + m] = f2bf(c1[r]);
        }
        // e[r] = D[quad*4+r][l15]: col 0 = s(row), col 1 = t(row)
        if (l15 == 0) {
            #pragma unroll
            for (int r = 0; r < 4; ++r) {
                int m = mt * 16 + quad * 4 + r;
                float s = e[r];
                e1s[m] = expf(s);
                e2s[m] = expf(0.2f * s);
            }
        } else if (l15 == 1) {
            #pragma unroll
            for (int r = 0; r < 4; ++r) {
                int m = mt * 16 + quad * 4 + r;
                rhot[m] = expf(-0.8f * e[r]);
            }
        }
    }
    __syncthreads();

    // ---------- Phase B: numerator MFMA (w' built in-register) + fp32 denominator ----------
    float rho[4];
    int iR[4];
    #pragma unroll
    for (int rt = 0; rt < 4; ++rt) {
        int rw = (wv * 4 + rt) * 16 + l15;
        iR[rt] = rw;
        rho[rt] = rhot[rw];
    }
    f32x4 acc[4][2];
    float dacc[4];
    #pragma unroll
    for (int rt = 0; rt < 4; ++rt) {
        acc[rt][0] = (f32x4){0.f, 0.f, 0.f, 0.f};
        acc[rt][1] = (f32x4){0.f, 0.f, 0.f, 0.f};
        dacc[rt] = 0.f;
    }

    for (int kb = 0; kb < 16; ++kb) {
        const int j0 = kb * 32 + quad * 8;
        f32x4 ev0 = *(const f32x4*)&e1s[j0], ev1 = *(const f32x4*)&e1s[j0 + 4];
        f32x4 fv0 = *(const f32x4*)&e2s[j0], fv1 = *(const f32x4*)&e2s[j0 + 4];
        short8 b0 = *(const short8*)&h_t[l15 * HSTR + j0];
        short8 b1 = *(const short8*)&h_t[(l15 + 16) * HSTR + j0];
        if ((kb >> 1) == wv) {
            // SLOW path (2 of 16 kb's): this wave's rows may self-intersect this j-block
            #pragma unroll
            for (int rt = 0; rt < 4; ++rt) {
                const bool selfkb = (kb == ((wv * 4 + rt) >> 1));
                float w8[8];
                #pragma unroll
                for (int jj = 0; jj < 8; ++jj) {
                    float e1 = (jj < 4) ? ev0[jj & 3] : ev1[jj & 3];
                    float e2 = (jj < 4) ? fv0[jj & 3] : fv1[jj & 3];
                    float w = fmaxf(e1, rho[rt] * e2);
                    if (selfkb && (j0 + jj == iR[rt])) w = 0.f;
                    w8[jj] = w;
                }
                dacc[rt] += ((w8[0] + w8[1]) + (w8[2] + w8[3]))
                          + ((w8[4] + w8[5]) + (w8[6] + w8[7]));
                union { unsigned u[4]; short8 s8; } au;
                #pragma unroll
                for (int pp = 0; pp < 4; ++pp)
                    au.u[pp] = cvt_pk_bf16(w8[2 * pp], w8[2 * pp + 1]);
                acc[rt][0] = __builtin_amdgcn_mfma_f32_16x16x32_bf16(au.s8, b0, acc[rt][0], 0, 0, 0);
                acc[rt][1] = __builtin_amdgcn_mfma_f32_16x16x32_bf16(au.s8, b1, acc[rt][1], 0, 0, 0);
            }
        } else {
            // FAST path (14 of 16): no self element possible — no per-jj mask
            #pragma unroll
            for (int rt = 0; rt < 4; ++rt) {
                float w8[8];
                #pragma unroll
                for (int jj = 0; jj < 8; ++jj) {
                    float e1 = (jj < 4) ? ev0[jj & 3] : ev1[jj & 3];
                    float e2 = (jj < 4) ? fv0[jj & 3] : fv1[jj & 3];
                    w8[jj] = fmaxf(e1, rho[rt] * e2);
                }
                dacc[rt] += ((w8[0] + w8[1]) + (w8[2] + w8[3]))
                          + ((w8[4] + w8[5]) + (w8[6] + w8[7]));
                union { unsigned u[4]; short8 s8; } au;
                #pragma unroll
                for (int pp = 0; pp < 4; ++pp)
                    au.u[pp] = cvt_pk_bf16(w8[2 * pp], w8[2 * pp + 1]);
                acc[rt][0] = __builtin_amdgcn_mfma_f32_16x16x32_bf16(au.s8, b0, acc[rt][0], 0, 0, 0);
                acc[rt][1] = __builtin_amdgcn_mfma_f32_16x16x32_bf16(au.s8, b1, acc[rt][1], 0, 0, 0);
            }
        }
    }

    // denominator: reduce the 4 quads (same row lives in lanes sharing l15)
    #pragma unroll
    for (int rt = 0; rt < 4; ++rt) {
        float D = dacc[rt];
        D += __shfl_xor(D, 16, 64);
        D += __shfl_xor(D, 32, 64);
        if (quad == 0) dinv[iR[rt]] = 0.125f / D;   // fold 1/H; same-wave read below
    }

    float* mbase = msgs8 + (size_t)blockIdx.x * (NN * DH);
    #pragma unroll
    for (int rt = 0; rt < 4; ++rt) {
        #pragma unroll
        for (int half = 0; half < 2; ++half) {
            #pragma unroll
            for (int r = 0; r < 4; ++r) {
                int row = (wv * 4 + rt) * 16 + quad * 4 + r;
                mbase[row * DH + half * 16 + l15] = acc[rt][half][r] * dinv[row];
            }
        }
    }
}

// GRU-style gated update. 512 blocks x 256 threads, 32 rows/block (4 rows/thread).
// Occupancy raised via MORE BLOCKS (2 blocks/CU = 2 waves/SIMD), NOT bigger blocks
// (1024-thr blocks pin VGPR=64 -> spill, see R4).
__global__ __launch_bounds__(256) void gru_kernel(
    const float* __restrict__ in_g,
    const float* __restrict__ hid_g,
    const float* __restrict__ bias_g,
    const float* __restrict__ Whr, const float* __restrict__ Whi,
    const float* __restrict__ Whm,
    const float* __restrict__ Wir, const float* __restrict__ bir,
    const float* __restrict__ Wii, const float* __restrict__ bii,
    const float* __restrict__ Win, const float* __restrict__ bin_,
    const float* __restrict__ msgs8,   // [B*8][512][32], slice = b*8+h
    float* __restrict__ out_g)
{
    __shared__ float xs[32 * 100];                // cols 0..63 = x, 64..95 = tanh(msum+bias)
    __shared__ unsigned short WtL[3 * 32 * 100];  // Wt[g][k][d] bf16 (96 d's used)

    const int t = threadIdx.x;
    const int rowbase = blockIdx.x * 32;          // 512 blocks x 32 rows
    const int bslice = blockIdx.x >> 4;           // batch of this block (32 | 512)
    const int r0 = (blockIdx.x & 15) * 32;        // row offset within batch

    // stage x: 32 rows x 64 cols, f32x4 (512 vec-ops, 2 iters)
    for (int idx = t; idx < 512; idx += 256) {
        int row = idx >> 4, dq = idx & 15;
        f32x4 v = *(const f32x4*)&in_g[(size_t)(rowbase + row) * 64 + dq * 4];
        *(f32x4*)&xs[row * 100 + dq * 4] = v;
    }
    // msgv = tanh(sum_h msgs8[b*8+h] + bias), vectorized f32x4 (1 iter)
    {
        int row = t >> 3, kq = t & 7;             // 256 = 32 rows x 8 k-quads
        size_t base = (size_t)bslice * (8 * NN * DH) + (size_t)(r0 + row) * DH + kq * 4;
        f32x4 s = {0.f, 0.f, 0.f, 0.f};
        #pragma unroll
        for (int h = 0; h < 8; ++h) {
            f32x4 v = *(const f32x4*)&msgs8[base + (size_t)h * (NN * DH)];
            s.x += v.x; s.y += v.y; s.z += v.z; s.w += v.w;
        }
        const float* bg = bias_g + kq * 4;
        float* dst = &xs[row * 100 + 64 + kq * 4];
        dst[0] = tanhf(s.x + bg[0]);
        dst[1] = tanhf(s.y + bg[1]);
        dst[2] = tanhf(s.z + bg[2]);
        dst[3] = tanhf(s.w + bg[3]);
    }
    // stage weights: 3 gates x 3072, simple loops (no div/mod)
    for (int idx = t; idx < 3072; idx += 256) {
        int d = idx >> 5, k2 = idx & 31;
        WtL[(0 * 32 + k2) * 100 + d] = f2bf((d < 64) ? Wir[d * 32 + k2] : Whr[(d - 64) * 32 + k2]);
        WtL[(1 * 32 + k2) * 100 + d] = f2bf((d < 64) ? Wii[d * 32 + k2] : Whi[(d - 64) * 32 + k2]);
        WtL[(2 * 32 + k2) * 100 + d] = f2bf((d < 64) ? Win[d * 32 + k2] : Whm[(d - 64) * 32 + k2]);
    }
    __syncthreads();

    const int k = t & 31, rg = t >> 5;            // rg in 0..7, 4 rows each
    const unsigned short* wp0 = &WtL[(0 * 32 + k) * 100];
    const unsigned short* wp1 = &WtL[(1 * 32 + k) * 100];
    const unsigned short* wp2 = &WtL[(2 * 32 + k) * 100];

    float pr[4], pi[4], xn[4], hm[4];
    #pragma unroll
    for (int r = 0; r < 4; ++r) { pr[r] = 0.f; pi[r] = 0.f; xn[r] = 0.f; hm[r] = 0.f; }

    for (int d0 = 0; d0 < 64; d0 += 4) {
        short4v wr4 = *(const short4v*)&wp0[d0];
        short4v wi4 = *(const short4v*)&wp1[d0];
        short4v wn4 = *(const short4v*)&wp2[d0];
        float wr[4], wi[4], wn[4];
        #pragma unroll
        for (int jj = 0; jj < 4; ++jj) {
            wr[jj] = bf2f((unsigned short)wr4[jj]);
            wi[jj] = bf2f((unsigned short)wi4[jj]);
            wn[jj] = bf2f((unsigned short)wn4[jj]);
        }
        #pragma unroll
        for (int r = 0; r < 4; ++r) {
            f32x4 xv = *(const f32x4*)&xs[(rg * 4 + r) * 100 + d0];
            #pragma unroll
            for (int jj = 0; jj < 4; ++jj) {
                pr[r] += xv[jj] * wr[jj];
                pi[r] += xv[jj] * wi[jj];
                xn[r] += xv[jj] * wn[jj];
            }
        }
    }
    for (int d0 = 64; d0 < 96; d0 += 4) {
        short4v wr4 = *(const short4v*)&wp0[d0];
        short4v wi4 = *(const short4v*)&wp1[d0];
        short4v wn4 = *(const short4v*)&wp2[d0];
        float wr[4], wi[4], wn[4];
        #pragma unroll
        for (int jj = 0; jj < 4; ++jj) {
            wr[jj] = bf2f((unsigned short)wr4[jj]);
            wi[jj] = bf2f((unsigned short)wi4[jj]);
            wn[jj] = bf2f((unsigned short)wn4[jj]);
        }
        #pragma unroll
        for (int r = 0; r < 4; ++r) {
            f32x4 xv = *(const f32x4*)&xs[(rg * 4 + r) * 100 + d0];
            #pragma unroll
            for (int jj = 0; jj < 4; ++jj) {
                pr[r] += xv[jj] * wr[jj];
                pi[r] += xv[jj] * wi[jj];
                hm[r] += xv[jj] * wn[jj];
            }
        }
    }

    const float bir_k = bir[k], bii_k = bii[k], bin_k = bin_[k];
    #pragma unroll
    for (int r = 0; r < 4; ++r) {
        int row = rowbase + rg * 4 + r;
        float m  = 1.f / (1.f + expf(-(pr[r] + bir_k)));
        float ig = 1.f / (1.f + expf(-(pi[r] + bii_k)));
        float nn = tanhf(xn[r] + bin_k + m * hm[r]);
        float ho = hid_g[(size_t)row * 32 + k];
        out_g[(size_t)row * 32 + k] = ig * nn + (1.f - ig) * ho;
    }
}

extern "C" void kernel_launch(void* const* d_in, const int* in_sizes, int n_in,
                              void* d_out, int out_size, void* d_ws, size_t ws_size,
                              hipStream_t stream)
{
    const float* inputs = (const float*)d_in[0];
    const float* hidden = (const float*)d_in[1];
    const float* linear = (const float*)d_in[2];
    const float* bias   = (const float*)d_in[3];
    const float* asrc   = (const float*)d_in[4];
    const float* atar   = (const float*)d_in[5];
    const float* Whr    = (const float*)d_in[6];
    const float* Whi    = (const float*)d_in[7];
    const float* Whm    = (const float*)d_in[8];
    const float* Wir    = (const float*)d_in[9];
    const float* bir    = (const float*)d_in[10];
    const float* Wii    = (const float*)d_in[11];
    const float* bii    = (const float*)d_in[12];
    const float* Win    = (const float*)d_in[13];
    const float* bin_   = (const float*)d_in[14];

    float* msgs8 = (float*)d_ws;   // [B*8][512][32] fp32, 16 MB
    attn_kernel<<<dim3(256), dim3(512), 0, stream>>>(inputs, linear, asrc, atar, msgs8);
    gru_kernel<<<dim3(512), dim3(256), 0, stream>>>(inputs, hidden, bias,
                                                    Whr, Whi, Whm,
                                                    Wir, bir, Wii, bii, Win, bin_,
                                                    msgs8, (float*)d_out);
}

// Round 15
// 115.626 us; speedup vs baseline: 1.0338x; 1.0338x over previous
//
#include <hip/hip_runtime.h>

#define NN 512
#define DIN 64
#define DH 32
#define HSTR 520   // h_t row stride (pad: 260 dw == 4 mod 32, keeps 16B alignment)

typedef __attribute__((ext_vector_type(8))) short short8;
typedef __attribute__((ext_vector_type(4))) short short4v;
typedef __attribute__((ext_vector_type(4))) float f32x4;

__device__ __forceinline__ float bf2f(unsigned short u) {
    return __uint_as_float(((unsigned)u) << 16);
}
__device__ __forceinline__ unsigned short f2bf(float x) {
    unsigned u = __float_as_uint(x);
    u += 0x7FFF + ((u >> 16) & 1);
    return (unsigned short)(u >> 16);
}
// packed RNE f32x2 -> bf16x2 (1 VALU op vs ~4 for scalar f2bf; same rounding)
__device__ __forceinline__ unsigned cvt_pk_bf16(float lo, float hi) {
    unsigned r;
    asm("v_cvt_pk_bf16_f32 %0, %1, %2" : "=v"(r) : "v"(lo), "v"(hi));
    return r;
}

// One block per (head, batch). 512 threads = 8 waves. R5-proven grid.
// EXACT R10 kernel — verified 116.2us / absmax 0.015625 (session best).
// TOOLCHAIN RULES (hard-won):
//  - 1024-thread blocks pin VGPR=64 regardless of __launch_bounds__ 2nd arg ->
//    massive scratch spill (R2-R4). Never.
//  - Synthesized bf16 register paths into phase-B MFMA (constant-splat B-frag
//    R11; paired-cvt_pk 8B LDS store R14) -> NaN on HW. Class closed.
//  - f32x2 pair math (R12) and scores-via-MFMA (R13) both regressed. Closed.
// VALU diet ladder (confirmed wins): R8 exp/max algebra + cvt_pk [-3.0];
// R9 self-mask peel + phase-A cvt_pk [-3.6]; R10 row-scale cancel [-3.3].
__global__ __launch_bounds__(512) void attn_kernel(
    const float* __restrict__ in_g,    // [B,512,64]
    const float* __restrict__ lin_g,   // [H,64,32]
    const float* __restrict__ asrc_g,  // [H,32]
    const float* __restrict__ atar_g,  // [H,32]
    float* __restrict__ msgs8)         // [B*8][512][32] fp32, slice = blockIdx.x
{
    __shared__ unsigned short h_t[DH * HSTR];       // 33280 B: h_t[c*HSTR + m] = h[m][c]
    __shared__ float e1s[NN], e2s[NN];              // j-side: e^s, e^{0.2s}
    __shared__ float rhot[NN];                      // i-side: e^{-0.8 t}
    __shared__ float dinv[NN];

    const int t = threadIdx.x;
    const int lane = t & 63, wv = t >> 6;
    const int l15 = lane & 15, quad = lane >> 4;
    const int hIdx = blockIdx.x & 7, bIdx = blockIdx.x >> 3;

    const float as_lo = asrc_g[hIdx * 32 + l15];
    const float as_hi = asrc_g[hIdx * 32 + l15 + 16];
    const float at_lo = atar_g[hIdx * 32 + l15];
    const float at_hi = atar_g[hIdx * 32 + l15 + 16];

    // ---------- Phase A: projection h = x @ W via MFMA ----------
    short8 bfrag[2][2];
    {
        const float* lp = lin_g + hIdx * (DIN * DH);
        for (int nt = 0; nt < 2; ++nt)
            for (int ks = 0; ks < 2; ++ks) {
                union { unsigned u[4]; short8 s8; } bu;
                #pragma unroll
                for (int jp = 0; jp < 4; ++jp) {
                    float lo = lp[(ks * 32 + quad * 8 + 2 * jp)     * DH + l15 + nt * 16];
                    float hi = lp[(ks * 32 + quad * 8 + 2 * jp + 1) * DH + l15 + nt * 16];
                    bu.u[jp] = cvt_pk_bf16(lo, hi);
                }
                bfrag[nt][ks] = bu.s8;
            }
    }
    const float* xb = in_g + (size_t)bIdx * (NN * DIN);
    for (int mi = 0; mi < 4; ++mi) {
        int mt = wv * 4 + mi;
        int row = mt * 16 + l15;
        const float* rp = xb + row * DIN + quad * 8;
        f32x4 x0 = *((const f32x4*)rp);
        f32x4 x1 = *((const f32x4*)(rp + 4));
        f32x4 x2 = *((const f32x4*)(rp + 32));
        f32x4 x3 = *((const f32x4*)(rp + 36));
        union { unsigned u[4]; short8 s8; } ua0, ua1;
        ua0.u[0] = cvt_pk_bf16(x0[0], x0[1]);
        ua0.u[1] = cvt_pk_bf16(x0[2], x0[3]);
        ua0.u[2] = cvt_pk_bf16(x1[0], x1[1]);
        ua0.u[3] = cvt_pk_bf16(x1[2], x1[3]);
        ua1.u[0] = cvt_pk_bf16(x2[0], x2[1]);
        ua1.u[1] = cvt_pk_bf16(x2[2], x2[3]);
        ua1.u[2] = cvt_pk_bf16(x3[0], x3[1]);
        ua1.u[3] = cvt_pk_bf16(x3[2], x3[3]);
        f32x4 c0 = {0.f, 0.f, 0.f, 0.f}, c1 = {0.f, 0.f, 0.f, 0.f};
        c0 = __builtin_amdgcn_mfma_f32_16x16x32_bf16(ua0.s8, bfrag[0][0], c0, 0, 0, 0);
        c0 = __builtin_amdgcn_mfma_f32_16x16x32_bf16(ua1.s8, bfrag[0][1], c0, 0, 0, 0);
        c1 = __builtin_amdgcn_mfma_f32_16x16x32_bf16(ua0.s8, bfrag[1][0], c1, 0, 0, 0);
        c1 = __builtin_amdgcn_mfma_f32_16x16x32_bf16(ua1.s8, bfrag[1][1], c1, 0, 0, 0);
        float ps[4], pt[4];
        #pragma unroll
        for (int r = 0; r < 4; ++r) {
            int m = mt * 16 + quad * 4 + r;
            h_t[l15 * HSTR + m]        = f2bf(c0[r]);
            h_t[(l15 + 16) * HSTR + m] = f2bf(c1[r]);
            ps[r] = c0[r] * as_lo + c1[r] * as_hi;
            pt[r] = c0[r] * at_lo + c1[r] * at_hi;
        }
        #pragma unroll
        for (int off = 1; off <= 8; off <<= 1) {
            #pragma unroll
            for (int r = 0; r < 4; ++r) {
                ps[r] += __shfl_xor(ps[r], off, 64);
                pt[r] += __shfl_xor(pt[r], off, 64);
            }
        }
        if (l15 < 4) {
            int r = l15;
            int m = mt * 16 + quad * 4 + r;
            float s = ps[r], tt = pt[r];
            e1s[m] = expf(s);   e2s[m] = expf(0.2f * s);
            rhot[m] = expf(-0.8f * tt);
        }
    }
    __syncthreads();

    // ---------- Phase B: numerator MFMA (w' built in-register) + fp32 denominator ----------
    float rho[4];
    int iR[4];
    #pragma unroll
    for (int rt = 0; rt < 4; ++rt) {
        int rw = (wv * 4 + rt) * 16 + l15;
        iR[rt] = rw;
        rho[rt] = rhot[rw];
    }
    f32x4 acc[4][2];
    float dacc[4];
    #pragma unroll
    for (int rt = 0; rt < 4; ++rt) {
        acc[rt][0] = (f32x4){0.f, 0.f, 0.f, 0.f};
        acc[rt][1] = (f32x4){0.f, 0.f, 0.f, 0.f};
        dacc[rt] = 0.f;
    }

    for (int kb = 0; kb < 16; ++kb) {
        const int j0 = kb * 32 + quad * 8;
        f32x4 ev0 = *(const f32x4*)&e1s[j0], ev1 = *(const f32x4*)&e1s[j0 + 4];
        f32x4 fv0 = *(const f32x4*)&e2s[j0], fv1 = *(const f32x4*)&e2s[j0 + 4];
        short8 b0 = *(const short8*)&h_t[l15 * HSTR + j0];
        short8 b1 = *(const short8*)&h_t[(l15 + 16) * HSTR + j0];
        if ((kb >> 1) == wv) {
            // SLOW path (2 of 16 kb's): this wave's rows may self-intersect this j-block
            #pragma unroll
            for (int rt = 0; rt < 4; ++rt) {
                const bool selfkb = (kb == ((wv * 4 + rt) >> 1));
                float w8[8];
                #pragma unroll
                for (int jj = 0; jj < 8; ++jj) {
                    float e1 = (jj < 4) ? ev0[jj & 3] : ev1[jj & 3];
                    float e2 = (jj < 4) ? fv0[jj & 3] : fv1[jj & 3];
                    float w = fmaxf(e1, rho[rt] * e2);
                    if (selfkb && (j0 + jj == iR[rt])) w = 0.f;
                    w8[jj] = w;
                }
                dacc[rt] += ((w8[0] + w8[1]) + (w8[2] + w8[3]))
                          + ((w8[4] + w8[5]) + (w8[6] + w8[7]));
                union { unsigned u[4]; short8 s8; } au;
                #pragma unroll
                for (int pp = 0; pp < 4; ++pp)
                    au.u[pp] = cvt_pk_bf16(w8[2 * pp], w8[2 * pp + 1]);
                acc[rt][0] = __builtin_amdgcn_mfma_f32_16x16x32_bf16(au.s8, b0, acc[rt][0], 0, 0, 0);
                acc[rt][1] = __builtin_amdgcn_mfma_f32_16x16x32_bf16(au.s8, b1, acc[rt][1], 0, 0, 0);
            }
        } else {
            // FAST path (14 of 16): no self element possible — no per-jj mask
            #pragma unroll
            for (int rt = 0; rt < 4; ++rt) {
                float w8[8];
                #pragma unroll
                for (int jj = 0; jj < 8; ++jj) {
                    float e1 = (jj < 4) ? ev0[jj & 3] : ev1[jj & 3];
                    float e2 = (jj < 4) ? fv0[jj & 3] : fv1[jj & 3];
                    w8[jj] = fmaxf(e1, rho[rt] * e2);
                }
                dacc[rt] += ((w8[0] + w8[1]) + (w8[2] + w8[3]))
                          + ((w8[4] + w8[5]) + (w8[6] + w8[7]));
                union { unsigned u[4]; short8 s8; } au;
                #pragma unroll
                for (int pp = 0; pp < 4; ++pp)
                    au.u[pp] = cvt_pk_bf16(w8[2 * pp], w8[2 * pp + 1]);
                acc[rt][0] = __builtin_amdgcn_mfma_f32_16x16x32_bf16(au.s8, b0, acc[rt][0], 0, 0, 0);
                acc[rt][1] = __builtin_amdgcn_mfma_f32_16x16x32_bf16(au.s8, b1, acc[rt][1], 0, 0, 0);
            }
        }
    }

    // denominator: reduce the 4 quads (same row lives in lanes sharing l15)
    #pragma unroll
    for (int rt = 0; rt < 4; ++rt) {
        float D = dacc[rt];
        D += __shfl_xor(D, 16, 64);
        D += __shfl_xor(D, 32, 64);
        if (quad == 0) dinv[iR[rt]] = 0.125f / D;   // fold 1/H; same-wave read below
    }

    float* mbase = msgs8 + (size_t)blockIdx.x * (NN * DH);
    #pragma unroll
    for (int rt = 0; rt < 4; ++rt) {
        #pragma unroll
        for (int half = 0; half < 2; ++half) {
            #pragma unroll
            for (int r = 0; r < 4; ++r) {
                int row = (wv * 4 + rt) * 16 + quad * 4 + r;
                mbase[row * DH + half * 16 + l15] = acc[rt][half][r] * dinv[row];
            }
        }
    }
}

// GRU-style gated update. 512 blocks x 256 threads, 32 rows/block (4 rows/thread).
// Occupancy raised via MORE BLOCKS (2 blocks/CU = 2 waves/SIMD), NOT bigger blocks
// (1024-thr blocks pin VGPR=64 -> spill, see R4).
__global__ __launch_bounds__(256) void gru_kernel(
    const float* __restrict__ in_g,
    const float* __restrict__ hid_g,
    const float* __restrict__ bias_g,
    const float* __restrict__ Whr, const float* __restrict__ Whi,
    const float* __restrict__ Whm,
    const float* __restrict__ Wir, const float* __restrict__ bir,
    const float* __restrict__ Wii, const float* __restrict__ bii,
    const float* __restrict__ Win, const float* __restrict__ bin_,
    const float* __restrict__ msgs8,   // [B*8][512][32], slice = b*8+h
    float* __restrict__ out_g)
{
    __shared__ float xs[32 * 100];                // cols 0..63 = x, 64..95 = tanh(msum+bias)
    __shared__ unsigned short WtL[3 * 32 * 100];  // Wt[g][k][d] bf16 (96 d's used)

    const int t = threadIdx.x;
    const int rowbase = blockIdx.x * 32;          // 512 blocks x 32 rows
    const int bslice = blockIdx.x >> 4;           // batch of this block (32 | 512)
    const int r0 = (blockIdx.x & 15) * 32;        // row offset within batch

    // stage x: 32 rows x 64 cols, f32x4 (512 vec-ops, 2 iters)
    for (int idx = t; idx < 512; idx += 256) {
        int row = idx >> 4, dq = idx & 15;
        f32x4 v = *(const f32x4*)&in_g[(size_t)(rowbase + row) * 64 + dq * 4];
        *(f32x4*)&xs[row * 100 + dq * 4] = v;
    }
    // msgv = tanh(sum_h msgs8[b*8+h] + bias), vectorized f32x4 (1 iter)
    {
        int row = t >> 3, kq = t & 7;             // 256 = 32 rows x 8 k-quads
        size_t base = (size_t)bslice * (8 * NN * DH) + (size_t)(r0 + row) * DH + kq * 4;
        f32x4 s = {0.f, 0.f, 0.f, 0.f};
        #pragma unroll
        for (int h = 0; h < 8; ++h) {
            f32x4 v = *(const f32x4*)&msgs8[base + (size_t)h * (NN * DH)];
            s.x += v.x; s.y += v.y; s.z += v.z; s.w += v.w;
        }
        const float* bg = bias_g + kq * 4;
        float* dst = &xs[row * 100 + 64 + kq * 4];
        dst[0] = tanhf(s.x + bg[0]);
        dst[1] = tanhf(s.y + bg[1]);
        dst[2] = tanhf(s.z + bg[2]);
        dst[3] = tanhf(s.w + bg[3]);
    }
    // stage weights: 3 gates x 3072, simple loops (no div/mod)
    for (int idx = t; idx < 3072; idx += 256) {
        int d = idx >> 5, k2 = idx & 31;
        WtL[(0 * 32 + k2) * 100 + d] = f2bf((d < 64) ? Wir[d * 32 + k2] : Whr[(d - 64) * 32 + k2]);
        WtL[(1 * 32 + k2) * 100 + d] = f2bf((d < 64) ? Wii[d * 32 + k2] : Whi[(d - 64) * 32 + k2]);
        WtL[(2 * 32 + k2) * 100 + d] = f2bf((d < 64) ? Win[d * 32 + k2] : Whm[(d - 64) * 32 + k2]);
    }
    __syncthreads();

    const int k = t & 31, rg = t >> 5;            // rg in 0..7, 4 rows each
    const unsigned short* wp0 = &WtL[(0 * 32 + k) * 100];
    const unsigned short* wp1 = &WtL[(1 * 32 + k) * 100];
    const unsigned short* wp2 = &WtL[(2 * 32 + k) * 100];

    float pr[4], pi[4], xn[4], hm[4];
    #pragma unroll
    for (int r = 0; r < 4; ++r) { pr[r] = 0.f; pi[r] = 0.f; xn[r] = 0.f; hm[r] = 0.f; }

    for (int d0 = 0; d0 < 64; d0 += 4) {
        short4v wr4 = *(const short4v*)&wp0[d0];
        short4v wi4 = *(const short4v*)&wp1[d0];
        short4v wn4 = *(const short4v*)&wp2[d0];
        float wr[4], wi[4], wn[4];
        #pragma unroll
        for (int jj = 0; jj < 4; ++jj) {
            wr[jj] = bf2f((unsigned short)wr4[jj]);
            wi[jj] = bf2f((unsigned short)wi4[jj]);
            wn[jj] = bf2f((unsigned short)wn4[jj]);
        }
        #pragma unroll
        for (int r = 0; r < 4; ++r) {
            f32x4 xv = *(const f32x4*)&xs[(rg * 4 + r) * 100 + d0];
            #pragma unroll
            for (int jj = 0; jj < 4; ++jj) {
                pr[r] += xv[jj] * wr[jj];
                pi[r] += xv[jj] * wi[jj];
                xn[r] += xv[jj] * wn[jj];
            }
        }
    }
    for (int d0 = 64; d0 < 96; d0 += 4) {
        short4v wr4 = *(const short4v*)&wp0[d0];
        short4v wi4 = *(const short4v*)&wp1[d0];
        short4v wn4 = *(const short4v*)&wp2[d0];
        float wr[4], wi[4], wn[4];
        #pragma unroll
        for (int jj = 0; jj < 4; ++jj) {
            wr[jj] = bf2f((unsigned short)wr4[jj]);
            wi[jj] = bf2f((unsigned short)wi4[jj]);
            wn[jj] = bf2f((unsigned short)wn4[jj]);
        }
        #pragma unroll
        for (int r = 0; r < 4; ++r) {
            f32x4 xv = *(const f32x4*)&xs[(rg * 4 + r) * 100 + d0];
            #pragma unroll
            for (int jj = 0; jj < 4; ++jj) {
                pr[r] += xv[jj] * wr[jj];
                pi[r] += xv[jj] * wi[jj];
                hm[r] += xv[jj] * wn[jj];
            }
        }
    }

    const float bir_k = bir[k], bii_k = bii[k], bin_k = bin_[k];
    #pragma unroll
    for (int r = 0; r < 4; ++r) {
        int row = rowbase + rg * 4 + r;
        float m  = 1.f / (1.f + expf(-(pr[r] + bir_k)));
        float ig = 1.f / (1.f + expf(-(pi[r] + bii_k)));
        float nn = tanhf(xn[r] + bin_k + m * hm[r]);
        float ho = hid_g[(size_t)row * 32 + k];
        out_g[(size_t)row * 32 + k] = ig * nn + (1.f - ig) * ho;
    }
}

extern "C" void kernel_launch(void* const* d_in, const int* in_sizes, int n_in,
                              void* d_out, int out_size, void* d_ws, size_t ws_size,
                              hipStream_t stream)
{
    const float* inputs = (const float*)d_in[0];
    const float* hidden = (const float*)d_in[1];
    const float* linear = (const float*)d_in[2];
    const float* bias   = (const float*)d_in[3];
    const float* asrc   = (const float*)d_in[4];
    const float* atar   = (const float*)d_in[5];
    const float* Whr    = (const float*)d_in[6];
    const float* Whi    = (const float*)d_in[7];
    const float* Whm    = (const float*)d_in[8];
    const float* Wir    = (const float*)d_in[9];
    const float* bir    = (const float*)d_in[10];
    const float* Wii    = (const float*)d_in[11];
    const float* bii    = (const float*)d_in[12];
    const float* Win    = (const float*)d_in[13];
    const float* bin_   = (const float*)d_in[14];

    float* msgs8 = (float*)d_ws;   // [B*8][512][32] fp32, 16 MB
    attn_kernel<<<dim3(256), dim3(512), 0, stream>>>(inputs, linear, asrc, atar, msgs8);
    gru_kernel<<<dim3(512), dim3(256), 0, stream>>>(inputs, hidden, bias,
                                                    Whr, Whi, Whm,
                                                    Wir, bir, Wii, bii, Win, bin_,
                                                    msgs8, (float*)d_out);
}